// Round 1
// baseline (303.366 us; speedup 1.0000x reference)
//
#include <hip/hip_runtime.h>
#include <math.h>

#define TT 128
#define BB 4
#define NT (BB*TT*TT)   // 65536 elements per [B,T,T] array
#define TEN3(b,x,y) (((b)*TT + (x))*TT + (y))

__device__ __forceinline__ float sigm(float x) { return 1.0f / (1.0f + __expf(-x)); }
__device__ __forceinline__ float4 ld4(const float* __restrict__ p) {
    return *reinterpret_cast<const float4*>(p);
}
__device__ __forceinline__ float4 mul4(const float4 a, const float4 b) {
    return make_float4(a.x*b.x, a.y*b.y, a.z*b.z, a.w*b.w);
}
__device__ __forceinline__ float4 fma4s(const float s, const float4 v, const float4 acc) {
    return make_float4(fmaf(s, v.x, acc.x), fmaf(s, v.y, acc.y),
                       fmaf(s, v.z, acc.z), fmaf(s, v.w, acc.w));
}
__device__ __forceinline__ float4 fma4v(const float4 s, const float4 v, const float4 acc) {
    return make_float4(fmaf(s.x, v.x, acc.x), fmaf(s.y, v.y, acc.y),
                       fmaf(s.z, v.z, acc.z), fmaf(s.w, v.w, acc.w));
}
__device__ __forceinline__ float dot4(const float4 a, const float4 b) {
    return a.x*b.x + a.y*b.y + a.z*b.z + a.w*b.w;
}

// Per-iteration prep: sigmoid of current q's, init accumulators with the base terms.
__global__ __launch_bounds__(256) void prep_kernel(
    const float* __restrict__ q_s, const float* __restrict__ q_h, const float* __restrict__ q_t,
    const float* __restrict__ span, const float* __restrict__ ph, const float* __restrict__ pt,
    float* __restrict__ sig_s, float* __restrict__ sig_h, float* __restrict__ sig_t,
    float* __restrict__ acc_s, float* __restrict__ acc_h, float* __restrict__ acc_t)
{
    const int idx = blockIdx.x * 256 + threadIdx.x;
    sig_s[idx] = sigm(q_s[idx]);
    sig_h[idx] = sigm(q_h[idx]);
    sig_t[idx] = sigm(q_t[idx]);
    acc_s[idx] = span[idx];
    acc_h[idx] = ph[idx];
    acc_t[idx] = pt[idx];
}

// K1: block fixed (b, j), loops over i (32-chunk, 4 rows in parallel).
// Handles: (1) span[j,k] += sh[i,j]*r_psh   (2) span[j,k] += st[i,k]*r_pst
//          (5) ph[i,j]  += sum_k ss[j,k]*r_psh
//          (4) span[i,j] += sum_k st[j,k]*f_pst   (12) pt[j,k] += ss[i,j]*f_pst
__global__ __launch_bounds__(128) void k1_kernel(
    const float* __restrict__ r_psh, const float* __restrict__ r_pst,
    const float* __restrict__ f_pst,
    const float* __restrict__ m_r, const float* __restrict__ m_f,
    const float* __restrict__ sig_s, const float* __restrict__ sig_h, const float* __restrict__ sig_t,
    float* __restrict__ acc_s, float* __restrict__ acc_h, float* __restrict__ acc_t)
{
    const int j = blockIdx.y, b = blockIdx.z;
    const int i0 = blockIdx.x * 32;
    const int sub = threadIdx.x >> 5;   // 0..3: which of 4 parallel rows
    const int kq  = threadIdx.x & 31;   // k-quad
    const int k4  = kq << 2;

    const float4 ss_jk = ld4(&sig_s[TEN3(b, j, k4)]);
    const float4 st_jk = ld4(&sig_t[TEN3(b, j, k4)]);

    float4 accspan = make_float4(0.f, 0.f, 0.f, 0.f);
    float4 accpt   = make_float4(0.f, 0.f, 0.f, 0.f);

    const long long base_bj = (long long)b * TT * TT * TT + (long long)j * TT + k4;

    #pragma unroll 2
    for (int step = 0; step < 8; ++step) {
        const int i = i0 + step * 4 + sub;
        const long long rb = base_bj + (long long)i * (TT * TT);

        const float4 vm  = ld4(&m_r[rb]);
        const float4 v1  = mul4(ld4(&r_psh[rb]), vm);
        const float4 v2  = mul4(ld4(&r_pst[rb]), vm);
        const float4 vmf = ld4(&m_f[rb]);
        const float4 v4  = mul4(ld4(&f_pst[rb]), vmf);

        const float  sh_ij = sig_h[TEN3(b, i, j)];
        const float  ss_ij = sig_s[TEN3(b, i, j)];
        const float4 st_ik = ld4(&sig_t[TEN3(b, i, k4)]);

        accspan = fma4s(sh_ij, v1, accspan);   // (1)
        accspan = fma4v(st_ik, v2, accspan);   // (2)
        accpt   = fma4s(ss_ij, v4, accpt);     // (12)

        float red5 = dot4(ss_jk, v1);          // (5) -> ph[b,i,j]
        float red4 = dot4(st_jk, v4);          // (4) -> span[b,i,j]
        #pragma unroll
        for (int off = 16; off; off >>= 1) {
            red5 += __shfl_xor(red5, off, 64);
            red4 += __shfl_xor(red4, off, 64);
        }
        if (kq == 0) {
            atomicAdd(&acc_h[TEN3(b, i, j)], red5);
            atomicAdd(&acc_s[TEN3(b, i, j)], red4);
        }
    }

    // combine sub pairs within each wave (lanes t and t^32), then atomics
    accspan.x += __shfl_xor(accspan.x, 32, 64);
    accspan.y += __shfl_xor(accspan.y, 32, 64);
    accspan.z += __shfl_xor(accspan.z, 32, 64);
    accspan.w += __shfl_xor(accspan.w, 32, 64);
    accpt.x += __shfl_xor(accpt.x, 32, 64);
    accpt.y += __shfl_xor(accpt.y, 32, 64);
    accpt.z += __shfl_xor(accpt.z, 32, 64);
    accpt.w += __shfl_xor(accpt.w, 32, 64);
    if (sub == 0 || sub == 2) {
        const int o = TEN3(b, j, k4);
        atomicAdd(&acc_s[o + 0], accspan.x);
        atomicAdd(&acc_s[o + 1], accspan.y);
        atomicAdd(&acc_s[o + 2], accspan.z);
        atomicAdd(&acc_s[o + 3], accspan.w);
        atomicAdd(&acc_t[o + 0], accpt.x);
        atomicAdd(&acc_t[o + 1], accpt.y);
        atomicAdd(&acc_t[o + 2], accpt.z);
        atomicAdd(&acc_t[o + 3], accpt.w);
    }
}

// K2: block fixed (b, i), loops over j (32-chunk, 4 rows in parallel; fully contiguous reads).
// Handles: (3) span[i,j] += sum_k sh[i,k]*f_psh    (8)  ph[i,k] += ss[i,j]*f_psh
//          (6) ph[i,j]  += sum_k sh[i,k]*s_h       (9)  pt[i,j] += sum_k st[i,k]*s_t
//          (7) ph[i,k]  += sh[j,k]*c_h             (11) pt[i,k] += st[j,k]*c_t
//          (10) pt[i,k] += ss[j,k]*r_pst
__global__ __launch_bounds__(128) void k2_kernel(
    const float* __restrict__ f_psh, const float* __restrict__ s_h, const float* __restrict__ s_t,
    const float* __restrict__ c_h, const float* __restrict__ c_t, const float* __restrict__ r_pst,
    const float* __restrict__ m_sp, const float* __restrict__ m_sb,
    const float* __restrict__ m_cp, const float* __restrict__ m_r,
    const float* __restrict__ sig_s, const float* __restrict__ sig_h, const float* __restrict__ sig_t,
    float* __restrict__ acc_s, float* __restrict__ acc_h, float* __restrict__ acc_t)
{
    const int i = blockIdx.y, b = blockIdx.z;
    const int j0 = blockIdx.x * 32;
    const int sub = threadIdx.x >> 5;
    const int kq  = threadIdx.x & 31;
    const int k4  = kq << 2;

    const float4 sh_ik = ld4(&sig_h[TEN3(b, i, k4)]);
    const float4 st_ik = ld4(&sig_t[TEN3(b, i, k4)]);

    float4 accph = make_float4(0.f, 0.f, 0.f, 0.f);
    float4 accpt = make_float4(0.f, 0.f, 0.f, 0.f);

    const long long base_bi = (long long)b * TT * TT * TT + (long long)i * (TT * TT) + k4;

    #pragma unroll 2
    for (int step = 0; step < 8; ++step) {
        const int j = j0 + step * 4 + sub;
        const long long rb = base_bi + (long long)j * TT;

        const float4 msp = ld4(&m_sp[rb]);
        const float4 v3  = mul4(ld4(&f_psh[rb]), msp);
        const float4 msb = ld4(&m_sb[rb]);
        const float4 v6  = mul4(ld4(&s_h[rb]), msb);
        const float4 v9  = mul4(ld4(&s_t[rb]), msb);
        const float4 mcp = ld4(&m_cp[rb]);
        const float4 v7  = mul4(ld4(&c_h[rb]), mcp);
        const float4 v11 = mul4(ld4(&c_t[rb]), mcp);
        const float4 mr  = ld4(&m_r[rb]);
        const float4 v10 = mul4(ld4(&r_pst[rb]), mr);

        const float  ss_ij = sig_s[TEN3(b, i, j)];
        const float4 sh_jk = ld4(&sig_h[TEN3(b, j, k4)]);
        const float4 st_jk = ld4(&sig_t[TEN3(b, j, k4)]);
        const float4 ss_jk = ld4(&sig_s[TEN3(b, j, k4)]);

        accph = fma4s(ss_ij, v3,  accph);   // (8)
        accph = fma4v(sh_jk, v7,  accph);   // (7)
        accpt = fma4v(st_jk, v11, accpt);   // (11)
        accpt = fma4v(ss_jk, v10, accpt);   // (10)

        float red3 = dot4(sh_ik, v3);       // (3) -> span[b,i,j]
        float red6 = dot4(sh_ik, v6);       // (6) -> ph[b,i,j]
        float red9 = dot4(st_ik, v9);       // (9) -> pt[b,i,j]
        #pragma unroll
        for (int off = 16; off; off >>= 1) {
            red3 += __shfl_xor(red3, off, 64);
            red6 += __shfl_xor(red6, off, 64);
            red9 += __shfl_xor(red9, off, 64);
        }
        if (kq == 0) {
            atomicAdd(&acc_s[TEN3(b, i, j)], red3);
            atomicAdd(&acc_h[TEN3(b, i, j)], red6);
            atomicAdd(&acc_t[TEN3(b, i, j)], red9);
        }
    }

    accph.x += __shfl_xor(accph.x, 32, 64);
    accph.y += __shfl_xor(accph.y, 32, 64);
    accph.z += __shfl_xor(accph.z, 32, 64);
    accph.w += __shfl_xor(accph.w, 32, 64);
    accpt.x += __shfl_xor(accpt.x, 32, 64);
    accpt.y += __shfl_xor(accpt.y, 32, 64);
    accpt.z += __shfl_xor(accpt.z, 32, 64);
    accpt.w += __shfl_xor(accpt.w, 32, 64);
    if (sub == 0 || sub == 2) {
        const int o = TEN3(b, i, k4);
        atomicAdd(&acc_h[o + 0], accph.x);
        atomicAdd(&acc_h[o + 1], accph.y);
        atomicAdd(&acc_h[o + 2], accph.z);
        atomicAdd(&acc_h[o + 3], accph.w);
        atomicAdd(&acc_t[o + 0], accpt.x);
        atomicAdd(&acc_t[o + 1], accpt.y);
        atomicAdd(&acc_t[o + 2], accpt.z);
        atomicAdd(&acc_t[o + 3], accpt.w);
    }
}

extern "C" void kernel_launch(void* const* d_in, const int* in_sizes, int n_in,
                              void* d_out, int out_size, void* d_ws, size_t ws_size,
                              hipStream_t stream)
{
    const float* span      = (const float*)d_in[0];
    const float* ph        = (const float*)d_in[1];
    const float* pt        = (const float*)d_in[2];
    const float* rspan_psh = (const float*)d_in[3];
    const float* rspan_pst = (const float*)d_in[4];
    const float* fspan_psh = (const float*)d_in[5];
    const float* fspan_pst = (const float*)d_in[6];
    const float* ph_sib    = (const float*)d_in[7];
    const float* pt_sib    = (const float*)d_in[8];
    const float* ph_cop    = (const float*)d_in[9];
    const float* pt_cop    = (const float*)d_in[10];
    const float* m_p2rspan = (const float*)d_in[11];
    const float* m_psib    = (const float*)d_in[12];
    const float* m_pcop    = (const float*)d_in[13];
    const float* m_pspan2r = (const float*)d_in[14];

    float* ws = (float*)d_ws;
    float* sig_s = ws + 0 * NT;
    float* sig_h = ws + 1 * NT;
    float* sig_t = ws + 2 * NT;
    float* A_s   = ws + 3 * NT;
    float* A_h   = ws + 4 * NT;
    float* A_t   = ws + 5 * NT;
    float* B_s   = ws + 6 * NT;
    float* B_h   = ws + 7 * NT;
    float* B_t   = ws + 8 * NT;
    float* O_s   = (float*)d_out;
    float* O_h   = O_s + NT;
    float* O_t   = O_s + 2 * NT;

    struct Iter { const float *qs, *qh, *qt; float *as, *ah, *at; };
    const Iter it[3] = {
        { span, ph, pt,  A_s, A_h, A_t },
        { A_s, A_h, A_t, B_s, B_h, B_t },
        { B_s, B_h, B_t, O_s, O_h, O_t },
    };

    const dim3 grid4(4, TT, BB);
    const dim3 blk(128);

    for (int t = 0; t < 3; ++t) {
        prep_kernel<<<NT / 256, 256, 0, stream>>>(
            it[t].qs, it[t].qh, it[t].qt, span, ph, pt,
            sig_s, sig_h, sig_t, it[t].as, it[t].ah, it[t].at);
        k1_kernel<<<grid4, blk, 0, stream>>>(
            rspan_psh, rspan_pst, fspan_pst, m_p2rspan, m_pspan2r,
            sig_s, sig_h, sig_t, it[t].as, it[t].ah, it[t].at);
        k2_kernel<<<grid4, blk, 0, stream>>>(
            fspan_psh, ph_sib, pt_sib, ph_cop, pt_cop, rspan_pst,
            m_pspan2r, m_psib, m_pcop, m_p2rspan,
            sig_s, sig_h, sig_t, it[t].as, it[t].ah, it[t].at);
    }
}